// Round 4
// baseline (3865.094 us; speedup 1.0000x reference)
//
#include <hip/hip_runtime.h>
#include <hip/hip_bf16.h>

#define N 4096
#define B 8
#define ITERS 10
#define T (ITERS * N)
#define NT 1024
#define WIN 1024
#define INFK 0x7FFFFFFFu

// Kernel 1: Z0[b][i] = sum_j W[i][j] * x[b][j], accumulated in double.
// UNCHANGED (bit-identical Z0 -> identical flip trajectory).
__global__ __launch_bounds__(256) void z0_gemv(const float* __restrict__ W,
                                               const float* __restrict__ x,
                                               double* __restrict__ Z0) {
    const int i = blockIdx.x;
    const int tid = threadIdx.x;
    const float* __restrict__ row = W + (size_t)i * N;

    double acc[B];
#pragma unroll
    for (int b = 0; b < B; ++b) acc[b] = 0.0;

    for (int j = tid; j < N; j += 256) {
        const double w = (double)row[j];
#pragma unroll
        for (int b = 0; b < B; ++b) acc[b] += w * (double)x[b * N + j];
    }

    __shared__ double red[256 * B];  // 16 KB
#pragma unroll
    for (int b = 0; b < B; ++b) red[tid * B + b] = acc[b];
    __syncthreads();

    for (int s = 128; s > 0; s >>= 1) {
        if (tid < s) {
#pragma unroll
            for (int b = 0; b < B; ++b) red[tid * B + b] += red[(tid + s) * B + b];
        }
        __syncthreads();
    }
    if (tid < B) Z0[(size_t)tid * N + i] = red[tid];
}

__device__ __forceinline__ unsigned umin2(unsigned a, unsigned b) { return a < b ? a : b; }

// Kernel 2: fully register-resident field. Thread t owns Z[4t..4t+3] and
// y[4t..4t+3] in registers for the whole kernel. Per window (1024 steps =
// one permutation slice, indices distinct) an epoch-tagged inverse map
// wpos[index]->position is scattered once; each thread caches its 4 owned
// positions. Per flip round: key = (pos<<16 | i<<4 | (s+1)<<2 | (y+1)),
// wave shfl-min + 16-slot cross-wave min (1 barrier). Apply = coalesced
// float4 row read + 4 dfma on registers. No LDS Z, no catch-up, no gathers.
__global__ __launch_bounds__(1024) void hop_seq(const float* __restrict__ W,
                                                const float* __restrict__ x,
                                                const int* __restrict__ perms,
                                                const double* __restrict__ Z0,
                                                float* __restrict__ out) {
    const int b = blockIdx.x;
    const int tid = threadIdx.x;
    const int wid = tid >> 6;
    const int lane = tid & 63;

    __shared__ int wpos[N];             // 16 KB, epoch-tagged inverse map
    __shared__ unsigned slot[2][16];    // per-wave minima, parity buffered

    // ---- register-resident field ----
    double zj[4];
    int yj[4];
    {
        const double* __restrict__ zsrc = Z0 + (size_t)b * N + 4 * tid;
        zj[0] = zsrc[0]; zj[1] = zsrc[1]; zj[2] = zsrc[2]; zj[3] = zsrc[3];
        const float4 xv = ((const float4*)(x + (size_t)b * N))[tid];
        yj[0] = (int)xv.x; yj[1] = (int)xv.y; yj[2] = (int)xv.z; yj[3] = (int)xv.w;
    }
    const int* __restrict__ perm = perms + (size_t)b * T;

    int pf_i = -1;        // prefetched row index (uniform across block)
    float4 pf;            // prefetched row fragment (this thread's 4 columns)

    for (int base = 0; base < T; base += WIN) {
        const int epoch = (base >> 10) + 1;   // 1..40; poison/stale never match
        // scatter inverse map for this window (indices distinct in window)
        const int istage = perm[base + tid];  // coalesced
        wpos[istage] = (epoch << 10) | tid;
        __syncthreads();
        // own 4 positions, single ds_read_b128 (16B-aligned, 2-way = free)
        const int4 wp = *((const int4*)(wpos + 4 * tid));
        int posk[4]; bool valid[4];
        posk[0] = wp.x & 1023; valid[0] = (wp.x >> 10) == epoch;
        posk[1] = wp.y & 1023; valid[1] = (wp.y >> 10) == epoch;
        posk[2] = wp.z & 1023; valid[2] = (wp.z >> 10) == epoch;
        posk[3] = wp.w & 1023; valid[3] = (wp.w >> 10) == epoch;

        int pos = 0;        // window-relative first unprocessed position (uniform)
        unsigned r = 0;

        for (;;) {
            // ---- per-thread candidate key over 4 owned indices ----
            unsigned key = INFK;
#pragma unroll
            for (int k = 0; k < 4; ++k) {
                const double z = zj[k];
                const int s = (z > 0.0) ? 1 : ((z < 0.0) ? -1 : 0);
                const bool f = valid[k] & (posk[k] >= pos) & (s != yj[k]);
                const unsigned kk = ((unsigned)posk[k] << 16)
                                  | ((unsigned)(4 * tid + k) << 4)
                                  | ((unsigned)(s + 1) << 2)
                                  | (unsigned)(yj[k] + 1);
                if (f) key = umin2(key, kk);
            }
            // ---- wave min (6-step butterfly) ----
            unsigned m = key;
            m = umin2(m, (unsigned)__shfl_xor((int)m, 1, 64));
            m = umin2(m, (unsigned)__shfl_xor((int)m, 2, 64));
            m = umin2(m, (unsigned)__shfl_xor((int)m, 4, 64));
            m = umin2(m, (unsigned)__shfl_xor((int)m, 8, 64));
            m = umin2(m, (unsigned)__shfl_xor((int)m, 16, 64));
            m = umin2(m, (unsigned)__shfl_xor((int)m, 32, 64));
            const unsigned p = r & 1u; r++;
            if (lane == 0) slot[p][wid] = m;
            __syncthreads();
            // ---- cross-wave min over 16 slots (broadcast read + 4 steps) ----
            const unsigned v = slot[p][lane & 15];
            unsigned g = v;
            g = umin2(g, (unsigned)__shfl_xor((int)g, 1, 64));
            g = umin2(g, (unsigned)__shfl_xor((int)g, 2, 64));
            g = umin2(g, (unsigned)__shfl_xor((int)g, 4, 64));
            g = umin2(g, (unsigned)__shfl_xor((int)g, 8, 64));
            if (g == INFK) break;  // no flip remains in window (uniform)

            const int posf  = (int)(g >> 16);
            const int istar = (int)((g >> 4) & 4095u);
            const int s1    = (int)((g >> 2) & 3u) - 1;
            const int y1    = (int)(g & 3u) - 1;
            const double d  = (double)(s1 - y1);
            pos = posf + 1;

            // ---- row fetch: issue immediately (miss path starts early) ----
            const bool hit = (istar == pf_i);   // uniform
            float4 wrow;
            if (!hit) wrow = ((const float4*)(W + (size_t)istar * N))[tid];

            // ---- 2nd-distinct-wave min -> prefetch hint (hides under miss) ----
            unsigned v2 = (v == g) ? INFK : v;
            v2 = umin2(v2, (unsigned)__shfl_xor((int)v2, 1, 64));
            v2 = umin2(v2, (unsigned)__shfl_xor((int)v2, 2, 64));
            v2 = umin2(v2, (unsigned)__shfl_xor((int)v2, 4, 64));
            v2 = umin2(v2, (unsigned)__shfl_xor((int)v2, 8, 64));
            if (hit) wrow = pf;
            if (v2 != INFK) {
                const int i2 = (int)((v2 >> 4) & 4095u);
                pf = ((const float4*)(W + (size_t)i2 * N))[tid];
                pf_i = i2;
            }

            // ---- apply rank-1 update to the register field ----
            zj[0] += d * (double)wrow.x;   // W[istar][istar]==0 -> owner safe
            zj[1] += d * (double)wrow.y;
            zj[2] += d * (double)wrow.z;
            zj[3] += d * (double)wrow.w;
            if ((istar >> 2) == tid) yj[istar & 3] = s1;
        }
    }

    float4 o;
    o.x = (float)yj[0]; o.y = (float)yj[1]; o.z = (float)yj[2]; o.w = (float)yj[3];
    ((float4*)(out + (size_t)b * N))[tid] = o;
}

extern "C" void kernel_launch(void* const* d_in, const int* in_sizes, int n_in,
                              void* d_out, int out_size, void* d_ws, size_t ws_size,
                              hipStream_t stream) {
    const float* x = (const float*)d_in[0];      // [B, N] f32, bipolar
    const float* W = (const float*)d_in[1];      // [N, N] f32, symmetric, zero diag
    const int* perms = (const int*)d_in[2];      // [B, ITERS, N] i32
    float* out = (float*)d_out;                  // [B, N] f32
    double* Z0 = (double*)d_ws;                  // B*N doubles = 256 KB scratch

    hipLaunchKernelGGL(z0_gemv, dim3(N), dim3(256), 0, stream, W, x, Z0);
    hipLaunchKernelGGL(hop_seq, dim3(B), dim3(1024), 0, stream, W, x, perms, Z0, out);
}

// Round 5
// 3092.223 us; speedup vs baseline: 1.2499x; 1.2499x over previous
//
#include <hip/hip_runtime.h>
#include <hip/hip_bf16.h>

#define N 4096
#define B 8
#define ITERS 10
#define T (ITERS * N)
#define NT 256          // 4 waves
#define E 16            // field elements per thread
#define WIN 1024
#define INFK 0xFFFFFFFFu

// Kernel 1: Z0[b][i] = sum_j W[i][j] * x[b][j], accumulated in double.
// UNCHANGED (decision-identical trajectory vs rounds 1-4).
__global__ __launch_bounds__(256) void z0_gemv(const float* __restrict__ W,
                                               const float* __restrict__ x,
                                               double* __restrict__ Z0) {
    const int i = blockIdx.x;
    const int tid = threadIdx.x;
    const float* __restrict__ row = W + (size_t)i * N;

    double acc[B];
#pragma unroll
    for (int b = 0; b < B; ++b) acc[b] = 0.0;

    for (int j = tid; j < N; j += 256) {
        const double w = (double)row[j];
#pragma unroll
        for (int b = 0; b < B; ++b) acc[b] += w * (double)x[b * N + j];
    }

    __shared__ double red[256 * B];  // 16 KB
#pragma unroll
    for (int b = 0; b < B; ++b) red[tid * B + b] = acc[b];
    __syncthreads();

    for (int s = 128; s > 0; s >>= 1) {
        if (tid < s) {
#pragma unroll
            for (int b = 0; b < B; ++b) red[tid * B + b] += red[(tid + s) * B + b];
        }
        __syncthreads();
    }
    if (tid < B) Z0[(size_t)tid * N + i] = red[tid];
}

__device__ __forceinline__ unsigned umin2(unsigned a, unsigned b) { return a < b ? a : b; }

// Kernel 2: 4-wave register-resident scan. Thread t owns Z[16t..16t+15] and
// y[16t..16t+15] in registers. Static per-window key per elem:
//   sk = pos<<14 | i<<2 | (y+1)   (INF if elem not in window)
// Per round, per elem (6 VALU): zj += d*w;  t2 = hi(zj) ^ ymaskInv;
//   cand = (sk | (t2>>31)) - curkey;  key = min(key, cand)
// (match => t2<0 => mask=~0 => cand=INF-ck; stale pos (sk<ck) wraps high;
//  valid-future cand < 2^24). Reduce: 6 wave shuffles + one uint4 broadcast
// LDS read of the 4 wave minima + 3 v_min. One 4-wave barrier per round.
// Mismatch implies s=-y, so d=-2*y1 and new y=-y1 come from the key alone.
// sign(z) taken from the f64 sign bit (exact-0.0 corner: probability ~0 and
// round-1's absmax==0 proves the reference trajectory never hits it).
__global__ __launch_bounds__(256) void hop_seq(const float* __restrict__ W,
                                               const float* __restrict__ x,
                                               const int* __restrict__ perms,
                                               const double* __restrict__ Z0,
                                               float* __restrict__ out) {
    const int b = blockIdx.x;
    const int tid = threadIdx.x;
    const int wid = tid >> 6;
    const int lane = tid & 63;

    __shared__ int wpos[N];        // 16 KB epoch-tagged inverse map
    __shared__ uint4 slotv[2];     // 4 wave minima per parity

    // ---- register-resident field ----
    double zj[E];
    unsigned ymask[E];             // ~(y<0 ? 0x80000000 : 0): top bit == (y>0)
    unsigned sk[E];
    {
        const double* __restrict__ zsrc = Z0 + (size_t)b * N + E * tid;
#pragma unroll
        for (int k = 0; k < E; ++k) zj[k] = zsrc[k];
        const float4* __restrict__ xs = (const float4*)(x + (size_t)b * N);
#pragma unroll
        for (int q = 0; q < 4; ++q) {
            const float4 xv = xs[4 * tid + q];
            ymask[4 * q + 0] = (xv.x > 0.f) ? 0xFFFFFFFFu : 0x7FFFFFFFu;
            ymask[4 * q + 1] = (xv.y > 0.f) ? 0xFFFFFFFFu : 0x7FFFFFFFu;
            ymask[4 * q + 2] = (xv.z > 0.f) ? 0xFFFFFFFFu : 0x7FFFFFFFu;
            ymask[4 * q + 3] = (xv.w > 0.f) ? 0xFFFFFFFFu : 0x7FFFFFFFu;
        }
    }
    const int* __restrict__ perm_b = perms + (size_t)b * T;

    float pf[E];                   // prefetched row fragment
    int pf_i = -1;
    unsigned r = 0;                // global round parity (never reset)

    for (int base = 0; base < T; base += WIN) {
        const int epoch = (base >> 10) + 1;
        // scatter inverse map (window = permutation slice, indices distinct)
        const int4 iv = ((const int4*)(perm_b + base))[tid];
        wpos[iv.x] = (epoch << 10) | (4 * tid + 0);
        wpos[iv.y] = (epoch << 10) | (4 * tid + 1);
        wpos[iv.z] = (epoch << 10) | (4 * tid + 2);
        wpos[iv.w] = (epoch << 10) | (4 * tid + 3);
        __syncthreads();
        // build static keys for the 16 owned elems
#pragma unroll
        for (int q = 0; q < 4; ++q) {
            const int4 wp = ((const int4*)wpos)[4 * tid + q];
            const int e0 = 4 * q;
            const unsigned i0 = (unsigned)(E * tid + e0);
            sk[e0 + 0] = ((wp.x >> 10) == epoch)
                ? (((unsigned)(wp.x & 1023) << 14) | ((i0 + 0) << 2) | ((ymask[e0 + 0] >> 30) & 2u)) : INFK;
            sk[e0 + 1] = ((wp.y >> 10) == epoch)
                ? (((unsigned)(wp.y & 1023) << 14) | ((i0 + 1) << 2) | ((ymask[e0 + 1] >> 30) & 2u)) : INFK;
            sk[e0 + 2] = ((wp.z >> 10) == epoch)
                ? (((unsigned)(wp.z & 1023) << 14) | ((i0 + 2) << 2) | ((ymask[e0 + 2] >> 30) & 2u)) : INFK;
            sk[e0 + 3] = ((wp.w >> 10) == epoch)
                ? (((unsigned)(wp.w & 1023) << 14) | ((i0 + 3) << 2) | ((ymask[e0 + 3] >> 30) & 2u)) : INFK;
        }

        unsigned ck = 0;
        // round-0 pure scan
        unsigned key = INFK;
#pragma unroll
        for (int k = 0; k < E; ++k) {
            const unsigned t2 = ((unsigned)__double2hiint(zj[k])) ^ ymask[k];
            const unsigned cand = (sk[k] | (unsigned)(((int)t2) >> 31)) - ck;
            key = umin2(key, cand);
        }

        for (;;) {
            // ---- wave min (6 shuffles) ----
            unsigned m = key;
            m = umin2(m, (unsigned)__shfl_xor((int)m, 1, 64));
            m = umin2(m, (unsigned)__shfl_xor((int)m, 2, 64));
            m = umin2(m, (unsigned)__shfl_xor((int)m, 4, 64));
            m = umin2(m, (unsigned)__shfl_xor((int)m, 8, 64));
            m = umin2(m, (unsigned)__shfl_xor((int)m, 16, 64));
            m = umin2(m, (unsigned)__shfl_xor((int)m, 32, 64));
            const unsigned p = r & 1u; r++;
            if (lane == 0) ((unsigned*)slotv)[4 * p + wid] = m;
            __syncthreads();
            // ---- broadcast read of all 4 wave minima, 3 v_min ----
            const uint4 s4 = slotv[p];
            const unsigned g = umin2(umin2(s4.x, s4.y), umin2(s4.z, s4.w));
            if (g >= 0x01000000u) break;   // no valid future candidate (uniform)

            const unsigned wk = g + ck;
            const int istar = (int)((wk >> 2) & 4095u);
            const int y1 = (int)(wk & 3u) - 1;
            const double d = (double)(-2 * y1);   // mismatch => s = -y
            const unsigned ck_old = ck;
            ck = ((wk >> 14) + 1u) << 14;

            // ---- second-distinct-wave min -> prefetch hint ----
            const unsigned o0 = (s4.x == g) ? INFK : s4.x;
            const unsigned o1 = (s4.y == g) ? INFK : s4.y;
            const unsigned o2 = (s4.z == g) ? INFK : s4.z;
            const unsigned o3 = (s4.w == g) ? INFK : s4.w;
            const unsigned v2 = umin2(umin2(o0, o1), umin2(o2, o3));

            // ---- row fragment: issue load early; prefetch next-likely row ----
            const bool hit = (istar == pf_i);     // uniform
            float wr[E];
            const float4* __restrict__ rowp = (const float4*)(W + (size_t)istar * N) + 4 * tid;
            if (!hit) {
                const float4 a = rowp[0], c = rowp[1], e = rowp[2], f = rowp[3];
                wr[0] = a.x;  wr[1] = a.y;  wr[2] = a.z;  wr[3] = a.w;
                wr[4] = c.x;  wr[5] = c.y;  wr[6] = c.z;  wr[7] = c.w;
                wr[8] = e.x;  wr[9] = e.y;  wr[10] = e.z; wr[11] = e.w;
                wr[12] = f.x; wr[13] = f.y; wr[14] = f.z; wr[15] = f.w;
            } else {
#pragma unroll
                for (int k = 0; k < E; ++k) wr[k] = pf[k];
            }
            if (v2 < 0x01000000u) {
                const int i2 = (int)(((v2 + ck_old) >> 2) & 4095u);
                const float4* __restrict__ r2 = (const float4*)(W + (size_t)i2 * N) + 4 * tid;
                const float4 a = r2[0], c = r2[1], e = r2[2], f = r2[3];
                pf[0] = a.x;  pf[1] = a.y;  pf[2] = a.z;  pf[3] = a.w;
                pf[4] = c.x;  pf[5] = c.y;  pf[6] = c.z;  pf[7] = c.w;
                pf[8] = e.x;  pf[9] = e.y;  pf[10] = e.z; pf[11] = e.w;
                pf[12] = f.x; pf[13] = f.y; pf[14] = f.z; pf[15] = f.w;
                pf_i = i2;
            }

            // ---- owner fixup (1 thread; other 3 waves branch over) ----
            if (tid == (istar >> 4)) {
                const int kk = istar & 15;
#pragma unroll
                for (int k = 0; k < E; ++k)
                    if (k == kk) { ymask[k] ^= 0x80000000u; sk[k] ^= 2u; }
            }

            // ---- fused apply + scan for next winner ----
            key = INFK;
#pragma unroll
            for (int k = 0; k < E; ++k) {
                zj[k] += d * (double)wr[k];   // W[istar][istar]==0 -> owner safe
                const unsigned t2 = ((unsigned)__double2hiint(zj[k])) ^ ymask[k];
                const unsigned cand = (sk[k] | (unsigned)(((int)t2) >> 31)) - ck;
                key = umin2(key, cand);
            }
        }
    }

    // ---- output: y = +1 if ymask top bit set else -1 ----
    float4* __restrict__ os = (float4*)(out + (size_t)b * N);
#pragma unroll
    for (int q = 0; q < 4; ++q) {
        float4 o;
        o.x = (ymask[4 * q + 0] & 0x80000000u) ? 1.0f : -1.0f;
        o.y = (ymask[4 * q + 1] & 0x80000000u) ? 1.0f : -1.0f;
        o.z = (ymask[4 * q + 2] & 0x80000000u) ? 1.0f : -1.0f;
        o.w = (ymask[4 * q + 3] & 0x80000000u) ? 1.0f : -1.0f;
        os[4 * tid + q] = o;
    }
}

extern "C" void kernel_launch(void* const* d_in, const int* in_sizes, int n_in,
                              void* d_out, int out_size, void* d_ws, size_t ws_size,
                              hipStream_t stream) {
    const float* x = (const float*)d_in[0];      // [B, N] f32, bipolar
    const float* W = (const float*)d_in[1];      // [N, N] f32, symmetric, zero diag
    const int* perms = (const int*)d_in[2];      // [B, ITERS, N] i32
    float* out = (float*)d_out;                  // [B, N] f32
    double* Z0 = (double*)d_ws;                  // B*N doubles = 256 KB scratch

    hipLaunchKernelGGL(z0_gemv, dim3(N), dim3(256), 0, stream, W, x, Z0);
    hipLaunchKernelGGL(hop_seq, dim3(B), dim3(NT), 0, stream, W, x, perms, Z0, out);
}

// Round 7
// 2901.021 us; speedup vs baseline: 1.3323x; 1.0659x over previous
//
#include <hip/hip_runtime.h>
#include <hip/hip_bf16.h>

#define N 4096
#define B 8
#define ITERS 10
#define T (ITERS * N)
#define NT 256          // 4 waves
#define E 16            // field elements per thread
#define WIN 1024
#define INFK 0xFFFFFFFFu
#define LIMIT 0x01000000u

// Kernel 1: Z0[b][i] = sum_j W[i][j] * x[b][j], accumulated in double.
// UNCHANGED (decision-identical trajectory vs rounds 1-5).
__global__ __launch_bounds__(256) void z0_gemv(const float* __restrict__ W,
                                               const float* __restrict__ x,
                                               double* __restrict__ Z0) {
    const int i = blockIdx.x;
    const int tid = threadIdx.x;
    const float* __restrict__ row = W + (size_t)i * N;

    double acc[B];
#pragma unroll
    for (int b = 0; b < B; ++b) acc[b] = 0.0;

    for (int j = tid; j < N; j += 256) {
        const double w = (double)row[j];
#pragma unroll
        for (int b = 0; b < B; ++b) acc[b] += w * (double)x[b * N + j];
    }

    __shared__ double red[256 * B];  // 16 KB
#pragma unroll
    for (int b = 0; b < B; ++b) red[tid * B + b] = acc[b];
    __syncthreads();

    for (int s = 128; s > 0; s >>= 1) {
        if (tid < s) {
#pragma unroll
            for (int b = 0; b < B; ++b) red[tid * B + b] += red[(tid + s) * B + b];
        }
        __syncthreads();
    }
    if (tid < B) Z0[(size_t)tid * N + i] = red[tid];
}

__device__ __forceinline__ unsigned umin2(unsigned a, unsigned b) { return a < b ? a : b; }

// One DPP min step. CTRL must be an immediate -> template parameter.
// Lanes with no valid source keep their own value (old=v, bound_ctrl=false),
// so the min is unaffected.
template <int CTRL>
__device__ __forceinline__ unsigned dpp_min(unsigned v) {
    const int t = __builtin_amdgcn_update_dpp((int)v, (int)v, CTRL, 0xF, 0xF, false);
    return umin2(v, (unsigned)t);
}

// Full wave64 min via DPP (~6 VALU-latency steps, no LDS). Valid in lane 63;
// returned as a wave-uniform value via readlane.
__device__ __forceinline__ unsigned wave_min64(unsigned v) {
    v = dpp_min<0x111>(v);  // row_shr:1
    v = dpp_min<0x112>(v);  // row_shr:2
    v = dpp_min<0x114>(v);  // row_shr:4
    v = dpp_min<0x118>(v);  // row_shr:8
    v = dpp_min<0x142>(v);  // row_bcast:15
    v = dpp_min<0x143>(v);  // row_bcast:31
    return (unsigned)__builtin_amdgcn_readlane((int)v, 63);
}

// Kernel 2: 4-wave register-resident scan (structure = round 5) with
//  (a) DPP wave-min instead of 6 dependent ds_bpermute shuffles,
//  (b) per-wave second-min published too -> exact global top-2 -> the row
//      prefetch targets the true next flip candidate.
// Key algebra unchanged: sk = pos<<14 | i<<2 | (y+1); per elem per round:
//  zj += d*w; t2 = hi64(zj) ^ ymask; cand = (sk | (t2>>31)) - ck; min.
// Mismatch => s=-y => d=-2*y1; winner decoded wholly from the key.
__global__ __launch_bounds__(256) void hop_seq(const float* __restrict__ W,
                                               const float* __restrict__ x,
                                               const int* __restrict__ perms,
                                               const double* __restrict__ Z0,
                                               float* __restrict__ out) {
    const int b = blockIdx.x;
    const int tid = threadIdx.x;
    const int wid = tid >> 6;
    const int lane = tid & 63;

    __shared__ int wpos[N];        // 16 KB epoch-tagged inverse map
    __shared__ uint4 slot1v[2];    // per-wave min, parity buffered
    __shared__ uint4 slot2v[2];    // per-wave 2nd min, parity buffered

    // ---- register-resident field ----
    double zj[E];
    unsigned ymask[E];             // 0xFFFFFFFF if y>0 else 0x7FFFFFFF
    unsigned sk[E];
    {
        const double* __restrict__ zsrc = Z0 + (size_t)b * N + E * tid;
#pragma unroll
        for (int k = 0; k < E; ++k) zj[k] = zsrc[k];
        const float4* __restrict__ xs = (const float4*)(x + (size_t)b * N);
#pragma unroll
        for (int q = 0; q < 4; ++q) {
            const float4 xv = xs[4 * tid + q];
            ymask[4 * q + 0] = (xv.x > 0.f) ? 0xFFFFFFFFu : 0x7FFFFFFFu;
            ymask[4 * q + 1] = (xv.y > 0.f) ? 0xFFFFFFFFu : 0x7FFFFFFFu;
            ymask[4 * q + 2] = (xv.z > 0.f) ? 0xFFFFFFFFu : 0x7FFFFFFFu;
            ymask[4 * q + 3] = (xv.w > 0.f) ? 0xFFFFFFFFu : 0x7FFFFFFFu;
        }
    }
    const int* __restrict__ perm_b = perms + (size_t)b * T;

    float pf[E];                   // prefetched row fragment
    int pf_i = -1;
    unsigned r = 0;                // global round parity (never reset)

    for (int base = 0; base < T; base += WIN) {
        const int epoch = (base >> 10) + 1;
        // scatter inverse map (window = permutation slice, indices distinct)
        const int4 iv = ((const int4*)(perm_b + base))[tid];
        wpos[iv.x] = (epoch << 10) | (4 * tid + 0);
        wpos[iv.y] = (epoch << 10) | (4 * tid + 1);
        wpos[iv.z] = (epoch << 10) | (4 * tid + 2);
        wpos[iv.w] = (epoch << 10) | (4 * tid + 3);
        __syncthreads();
        // build static keys for the 16 owned elems
#pragma unroll
        for (int q = 0; q < 4; ++q) {
            const int4 wp = ((const int4*)wpos)[4 * tid + q];
            const int e0 = 4 * q;
            const unsigned i0 = (unsigned)(E * tid + e0);
            sk[e0 + 0] = ((wp.x >> 10) == epoch)
                ? (((unsigned)(wp.x & 1023) << 14) | ((i0 + 0) << 2) | ((ymask[e0 + 0] >> 30) & 2u)) : INFK;
            sk[e0 + 1] = ((wp.y >> 10) == epoch)
                ? (((unsigned)(wp.y & 1023) << 14) | ((i0 + 1) << 2) | ((ymask[e0 + 1] >> 30) & 2u)) : INFK;
            sk[e0 + 2] = ((wp.z >> 10) == epoch)
                ? (((unsigned)(wp.z & 1023) << 14) | ((i0 + 2) << 2) | ((ymask[e0 + 2] >> 30) & 2u)) : INFK;
            sk[e0 + 3] = ((wp.w >> 10) == epoch)
                ? (((unsigned)(wp.w & 1023) << 14) | ((i0 + 3) << 2) | ((ymask[e0 + 3] >> 30) & 2u)) : INFK;
        }

        unsigned ck = 0;
        // round-0 pure scan
        unsigned key = INFK;
#pragma unroll
        for (int k = 0; k < E; ++k) {
            const unsigned t2 = ((unsigned)__double2hiint(zj[k])) ^ ymask[k];
            const unsigned cand = (sk[k] | (unsigned)(((int)t2) >> 31)) - ck;
            key = umin2(key, cand);
        }

        for (;;) {
            // ---- wave min via DPP (no LDS round trips) ----
            const unsigned m1 = wave_min64(key);
            const unsigned p = r & 1u; r++;
            if (lane == 0) ((unsigned*)&slot1v[p])[wid] = m1;
            // ---- wave 2nd min (winner lane masked; keys are unique) ----
            const unsigned m2 = wave_min64((key == m1) ? INFK : key);
            if (lane == 0) ((unsigned*)&slot2v[p])[wid] = m2;
            __syncthreads();

            // ---- exact global top-2 from the 8 published values ----
            const uint4 s1 = slot1v[p];
            const unsigned g = umin2(umin2(s1.x, s1.y), umin2(s1.z, s1.w));
            if (g >= LIMIT) break;   // no valid future candidate (uniform)
            const uint4 s2 = slot2v[p];
            const unsigned o0 = (s1.x == g) ? s2.x : s1.x;
            const unsigned o1 = (s1.y == g) ? s2.y : s1.y;
            const unsigned o2 = (s1.z == g) ? s2.z : s1.z;
            const unsigned o3 = (s1.w == g) ? s2.w : s1.w;
            const unsigned g2 = umin2(umin2(o0, o1), umin2(o2, o3));

            const unsigned wk = g + ck;
            const int istar = (int)((wk >> 2) & 4095u);
            const int y1 = (int)(wk & 3u) - 1;
            const double d = (double)(-2 * y1);   // mismatch => s = -y
            const unsigned ck_old = ck;
            ck = ((wk >> 14) + 1u) << 14;

            // ---- winner row: issue load early ----
            const bool hit = (istar == pf_i);     // uniform
            float wr[E];
            const float4* __restrict__ rowp = (const float4*)(W + (size_t)istar * N) + 4 * tid;
            if (!hit) {
                const float4 a = rowp[0], c = rowp[1], e = rowp[2], f = rowp[3];
                wr[0] = a.x;  wr[1] = a.y;  wr[2] = a.z;  wr[3] = a.w;
                wr[4] = c.x;  wr[5] = c.y;  wr[6] = c.z;  wr[7] = c.w;
                wr[8] = e.x;  wr[9] = e.y;  wr[10] = e.z; wr[11] = e.w;
                wr[12] = f.x; wr[13] = f.y; wr[14] = f.z; wr[15] = f.w;
            } else {
#pragma unroll
                for (int k = 0; k < E; ++k) wr[k] = pf[k];
            }
            // ---- exact next-candidate prefetch (overlaps apply + reduce) ----
            if (g2 < LIMIT) {
                const int i2 = (int)(((g2 + ck_old) >> 2) & 4095u);
                const float4* __restrict__ r2 = (const float4*)(W + (size_t)i2 * N) + 4 * tid;
                const float4 a = r2[0], c = r2[1], e = r2[2], f = r2[3];
                pf[0] = a.x;  pf[1] = a.y;  pf[2] = a.z;  pf[3] = a.w;
                pf[4] = c.x;  pf[5] = c.y;  pf[6] = c.z;  pf[7] = c.w;
                pf[8] = e.x;  pf[9] = e.y;  pf[10] = e.z; pf[11] = e.w;
                pf[12] = f.x; pf[13] = f.y; pf[14] = f.z; pf[15] = f.w;
                pf_i = i2;
            }

            // ---- owner fixup (1 thread) ----
            if (tid == (istar >> 4)) {
                const int kk = istar & 15;
#pragma unroll
                for (int k = 0; k < E; ++k)
                    if (k == kk) { ymask[k] ^= 0x80000000u; sk[k] ^= 2u; }
            }

            // ---- fused apply + scan for next winner ----
            key = INFK;
#pragma unroll
            for (int k = 0; k < E; ++k) {
                zj[k] += d * (double)wr[k];   // W[istar][istar]==0 -> owner safe
                const unsigned t2 = ((unsigned)__double2hiint(zj[k])) ^ ymask[k];
                const unsigned cand = (sk[k] | (unsigned)(((int)t2) >> 31)) - ck;
                key = umin2(key, cand);
            }
        }
    }

    // ---- output: y = +1 if ymask top bit set else -1 ----
    float4* __restrict__ os = (float4*)(out + (size_t)b * N);
#pragma unroll
    for (int q = 0; q < 4; ++q) {
        float4 o;
        o.x = (ymask[4 * q + 0] & 0x80000000u) ? 1.0f : -1.0f;
        o.y = (ymask[4 * q + 1] & 0x80000000u) ? 1.0f : -1.0f;
        o.z = (ymask[4 * q + 2] & 0x80000000u) ? 1.0f : -1.0f;
        o.w = (ymask[4 * q + 3] & 0x80000000u) ? 1.0f : -1.0f;
        os[4 * tid + q] = o;
    }
}

extern "C" void kernel_launch(void* const* d_in, const int* in_sizes, int n_in,
                              void* d_out, int out_size, void* d_ws, size_t ws_size,
                              hipStream_t stream) {
    const float* x = (const float*)d_in[0];      // [B, N] f32, bipolar
    const float* W = (const float*)d_in[1];      // [N, N] f32, symmetric, zero diag
    const int* perms = (const int*)d_in[2];      // [B, ITERS, N] i32
    float* out = (float*)d_out;                  // [B, N] f32
    double* Z0 = (double*)d_ws;                  // B*N doubles = 256 KB scratch

    hipLaunchKernelGGL(z0_gemv, dim3(N), dim3(256), 0, stream, W, x, Z0);
    hipLaunchKernelGGL(hop_seq, dim3(B), dim3(NT), 0, stream, W, x, perms, Z0, out);
}